// Round 3
// baseline (940.986 us; speedup 1.0000x reference)
//
#include <hip/hip_runtime.h>
#include <hip/hip_bf16.h>
#include <math.h>

typedef __bf16 bf16_t;
typedef __attribute__((ext_vector_type(8))) __bf16 bf16x8;
typedef __attribute__((ext_vector_type(4))) __bf16 bf16x4;
typedef __attribute__((ext_vector_type(4))) float f32x4;

#define L_TOK 4680
#define DIM   1536
#define NH    12
#define HD    128
#define FRAME 1560
#define LPAD  4736
#define SCALE 0.08838834764831845f   // 1/sqrt(128)

__device__ __forceinline__ void gl_lds16(const bf16_t* g, bf16_t* l) {
  __builtin_amdgcn_global_load_lds(
      (const __attribute__((address_space(1))) unsigned int*)(g),
      (__attribute__((address_space(3))) unsigned int*)(l),
      16, 0, 0);
}

// ---------------- fp32 -> bf16 cast ----------------
__global__ __launch_bounds__(256) void cast_f32_bf16(const float* __restrict__ in,
                                                     bf16_t* __restrict__ out, int n4) {
  int i = blockIdx.x * 256 + threadIdx.x;
  if (i >= n4) return;
  float4 v = ((const float4*)in)[i];
  bf16x4 o;
  o[0] = (__bf16)v.x; o[1] = (__bf16)v.y; o[2] = (__bf16)v.z; o[3] = (__bf16)v.w;
  ((bf16x4*)out)[i] = o;
}

// ---------------- fused QKV GEMM: C = X * W^T + b ----------------
__global__ __launch_bounds__(256) void gemm_qkv(
    const bf16_t* __restrict__ X,
    const bf16_t* __restrict__ Wq, const bf16_t* __restrict__ Wk, const bf16_t* __restrict__ Wv,
    const float* __restrict__ bq, const float* __restrict__ bk, const float* __restrict__ bv,
    bf16_t* __restrict__ Qo, bf16_t* __restrict__ Ko, bf16_t* __restrict__ Vt)
{
  __shared__ __align__(16) bf16_t Al[128 * 32];
  __shared__ __align__(16) bf16_t Bl[128 * 32];
  const int m0 = blockIdx.x * 128;
  const int nb = blockIdx.y;
  const int seg = nb / 12;
  const int n0 = (nb % 12) * 128;
  const bf16_t* W   = (seg == 0) ? Wq : (seg == 1) ? Wk : Wv;
  const float* bias = (seg == 0) ? bq : (seg == 1) ? bk : bv;

  const int tid = threadIdx.x;
  const int wave = tid >> 6, lane = tid & 63;
  const int quad = lane >> 4, l15 = lane & 15;
  const int wm = (wave >> 1) * 64, wn = (wave & 1) * 64;

  f32x4 acc[4][4];
#pragma unroll
  for (int i = 0; i < 4; ++i)
#pragma unroll
    for (int j = 0; j < 4; ++j) acc[i][j] = (f32x4){0.f, 0.f, 0.f, 0.f};

  const int c0 = wave * 2;
  const int fi0 = c0 * 512 + lane * 8;
  const int r0 = fi0 >> 5, col0 = fi0 & 31;
  const int fi1 = fi0 + 512;
  const int r1 = fi1 >> 5, col1 = fi1 & 31;

  const bf16_t* agp0 = X + (size_t)(m0 + r0) * DIM + col0;
  const bf16_t* agp1 = X + (size_t)(m0 + r1) * DIM + col1;
  const bf16_t* bgp0 = W + (size_t)(n0 + r0) * DIM + col0;
  const bf16_t* bgp1 = W + (size_t)(n0 + r1) * DIM + col1;
  bf16_t* al0 = Al + c0 * 512 + lane * 8;
  bf16_t* al1 = al0 + 512;
  bf16_t* bl0 = Bl + c0 * 512 + lane * 8;
  bf16_t* bl1 = bl0 + 512;

  for (int k0 = 0; k0 < DIM; k0 += 32) {
    __syncthreads();
    gl_lds16(agp0 + k0, al0);
    gl_lds16(agp1 + k0, al1);
    gl_lds16(bgp0 + k0, bl0);
    gl_lds16(bgp1 + k0, bl1);
    __syncthreads();
    bf16x8 af[4], bfg[4];
#pragma unroll
    for (int i = 0; i < 4; ++i) {
      af[i]  = *(const bf16x8*)(Al + (wm + i * 16 + l15) * 32 + quad * 8);
      bfg[i] = *(const bf16x8*)(Bl + (wn + i * 16 + l15) * 32 + quad * 8);
    }
#pragma unroll
    for (int i = 0; i < 4; ++i)
#pragma unroll
      for (int j = 0; j < 4; ++j)
        acc[i][j] = __builtin_amdgcn_mfma_f32_16x16x32_bf16(af[i], bfg[j], acc[i][j], 0, 0, 0);
  }

  if (seg < 2) {
    bf16_t* Out = (seg == 0) ? Qo : Ko;
#pragma unroll
    for (int i = 0; i < 4; ++i) {
#pragma unroll
      for (int j = 0; j < 4; ++j) {
        const int n = n0 + wn + j * 16 + l15;
        const float bb = bias[n];
#pragma unroll
        for (int r = 0; r < 4; ++r) {
          const int m = m0 + wm + i * 16 + quad * 4 + r;
          if (m < L_TOK) Out[(size_t)m * DIM + n] = (bf16_t)(acc[i][j][r] + bb);
        }
      }
    }
  } else {
#pragma unroll
    for (int i = 0; i < 4; ++i) {
      const int mb = m0 + wm + i * 16 + quad * 4;
      if (mb < L_TOK) {
#pragma unroll
        for (int j = 0; j < 4; ++j) {
          const int n = n0 + wn + j * 16 + l15;
          const float bb = bias[n];
          bf16x4 p;
          p[0] = (__bf16)(acc[i][j][0] + bb);
          p[1] = (__bf16)(acc[i][j][1] + bb);
          p[2] = (__bf16)(acc[i][j][2] + bb);
          p[3] = (__bf16)(acc[i][j][3] + bb);
          *(bf16x4*)(Vt + (size_t)n * LPAD + mb) = p;
        }
      }
    }
  }
}

// ---------------- RMSNorm + RoPE, in place on Q and K ----------------
__global__ __launch_bounds__(256) void rmsnorm_rope(
    bf16_t* __restrict__ Q, bf16_t* __restrict__ K,
    const float* __restrict__ gq, const float* __restrict__ gk,
    const float* __restrict__ freqs)
{
  const int l = blockIdx.x;
  const int tid = threadIdx.x;
  const int wave = tid >> 6, lane = tid & 63;
  bf16_t* qrow = Q + (size_t)l * DIM;
  bf16_t* krow = K + (size_t)l * DIM;

  unsigned int qb[3], kb[3];
  float sq = 0.f, sk = 0.f;
#pragma unroll
  for (int s = 0; s < 3; ++s) {
    const int p = s * 256 + tid;
    qb[s] = *(const unsigned int*)(qrow + 2 * p);
    kb[s] = *(const unsigned int*)(krow + 2 * p);
    const __bf16* qh = (const __bf16*)&qb[s];
    const __bf16* kh = (const __bf16*)&kb[s];
    const float q0 = (float)qh[0], q1 = (float)qh[1];
    const float k0 = (float)kh[0], k1 = (float)kh[1];
    sq += q0 * q0 + q1 * q1;
    sk += k0 * k0 + k1 * k1;
  }
#pragma unroll
  for (int off = 1; off < 64; off <<= 1) {
    sq += __shfl_xor(sq, off);
    sk += __shfl_xor(sk, off);
  }
  __shared__ float rq_s[4], rk_s[4];
  if (lane == 0) { rq_s[wave] = sq; rk_s[wave] = sk; }
  __syncthreads();
  sq = rq_s[0] + rq_s[1] + rq_s[2] + rq_s[3];
  sk = rk_s[0] + rk_s[1] + rk_s[2] + rk_s[3];
  const float rnq = rsqrtf(sq * (1.f / DIM) + 1e-6f);
  const float rnk = rsqrtf(sk * (1.f / DIM) + 1e-6f);

  const int t = l / FRAME;
  const int rem = l - t * FRAME;
  const int hh = rem / 52;
  const int ww = rem - hh * 52;

#pragma unroll
  for (int s = 0; s < 3; ++s) {
    const int p = s * 256 + tid;
    const int j = p & 63;
    const int sel = (j < 22) ? t : (j < 43) ? hh : ww;
    const float ang = freqs[sel * 64 + j];
    float sn, cs;
    __sincosf(ang, &sn, &cs);
    const __bf16* qh = (const __bf16*)&qb[s];
    const __bf16* kh = (const __bf16*)&kb[s];
    {
      const float g0 = gq[2 * p], g1 = gq[2 * p + 1];
      const float re = (float)qh[0] * rnq * g0;
      const float im = (float)qh[1] * rnq * g1;
      unsigned int o;
      __bf16* oh = (__bf16*)&o;
      oh[0] = (__bf16)((re * cs - im * sn) * SCALE);
      oh[1] = (__bf16)((re * sn + im * cs) * SCALE);
      *(unsigned int*)(qrow + 2 * p) = o;
    }
    {
      const float g0 = gk[2 * p], g1 = gk[2 * p + 1];
      const float re = (float)kh[0] * rnk * g0;
      const float im = (float)kh[1] * rnk * g1;
      unsigned int o;
      __bf16* oh = (__bf16*)&o;
      oh[0] = (__bf16)(re * cs - im * sn);
      oh[1] = (__bf16)(re * sn + im * cs);
      *(unsigned int*)(krow + 2 * p) = o;
    }
  }
}

// ---------------- flash attention v2 ----------------
// block = 128 q-rows x 1 head; 4 waves x 32 q-rows; 64-key tiles; 16x16x32 MFMA.
// XOR-swizzled K/V LDS; register softmax (shfl butterflies for max);
// ones-column V tile (nt=8) accumulates the denominator inside PV MFMA.
__global__ __launch_bounds__(256) void attn(
    const bf16_t* __restrict__ Q, const bf16_t* __restrict__ K,
    const bf16_t* __restrict__ Vt, bf16_t* __restrict__ O)
{
  __shared__ __align__(16) bf16_t Kl[64 * 128];    // [key][d], 16B chunks swizzled ^ (key&7)
  __shared__ __align__(16) bf16_t Vl[144 * 64];    // [d][key] swizzled; rows 128..143: ones tile
  __shared__ __align__(16) bf16_t Pl[4][32 * 72];  // per-wave P[q][key], row stride 72

  const int qb = (int)gridDim.x - 1 - (int)blockIdx.x;  // heavy tiles first
  const int h  = blockIdx.y;
  const int tid = threadIdx.x;
  const int wave = tid >> 6, lane = tid & 63;
  const int quad = lane >> 4, l15 = lane & 15;
  const int q0 = qb * 128;
  const int qw = q0 + wave * 32;

  // ones tile init (rows 128..143 of Vl): row 128 = 1.0, rows 129..143 = 0
  {
    const int r = tid >> 4, c4 = (tid & 15) * 4;
    const bf16_t v = (r == 0) ? (bf16_t)1.0f : (bf16_t)0.0f;
    bf16x4 vv = {v, v, v, v};
    *(bf16x4*)(Vl + (128 + r) * 64 + c4) = vv;
  }

  // Q fragments in registers (A-layout), 32 rows per wave (mt=0,1)
  bf16x8 qf[2][4];
#pragma unroll
  for (int mt = 0; mt < 2; ++mt) {
    const int qrow = qw + mt * 16 + l15;
    const bf16_t* qp = Q + (size_t)qrow * DIM + h * HD + quad * 8;
#pragma unroll
    for (int ds = 0; ds < 4; ++ds) qf[mt][ds] = *(const bf16x8*)(qp + ds * 32);
  }

  int kendv[2][4];
#pragma unroll
  for (int mt = 0; mt < 2; ++mt)
#pragma unroll
    for (int r = 0; r < 4; ++r) {
      int row = qw + mt * 16 + quad * 4 + r;
      if (row > L_TOK - 1) row = L_TOK - 1;
      kendv[mt][r] = FRAME * (row / FRAME + 1);
    }
  const int kend_blk = FRAME * (q0 / FRAME + 1);   // min kend over block

  f32x4 m_run[2], oacc[2][9];
#pragma unroll
  for (int mt = 0; mt < 2; ++mt) {
    m_run[mt] = (f32x4){-3.0e38f, -3.0e38f, -3.0e38f, -3.0e38f};
#pragma unroll
    for (int nt = 0; nt < 9; ++nt) oacc[mt][nt] = (f32x4){0.f, 0.f, 0.f, 0.f};
  }

  int lastl = q0 + 127; if (lastl > L_TOK - 1) lastl = L_TOK - 1;
  const int nkt = (FRAME * (lastl / FRAME + 1) + 63) >> 6;

  for (int kt = 0; kt < nkt; ++kt) {
    const int kb = kt * 64;

    // prefetch staging data into regs (overlaps with previous tile's tail)
    uint4 ku[4], vu[4];
#pragma unroll
    for (int it = 0; it < 4; ++it) {
      const int c = tid + it * 256;
      const int r = c >> 4, cc = c & 15;
      ku[it] = *(const uint4*)(K + (size_t)(kb + r) * DIM + h * HD + cc * 8);
      const int d = c >> 3, c8 = c & 7;
      vu[it] = *(const uint4*)(Vt + (size_t)(h * HD + d) * LPAD + kb + c8 * 8);
    }
    __syncthreads();
#pragma unroll
    for (int it = 0; it < 4; ++it) {
      const int c = tid + it * 256;
      const int r = c >> 4, cc = c & 15;
      *(uint4*)(Kl + r * 128 + ((cc ^ (r & 7)) * 8)) = ku[it];
      const int d = c >> 3, c8 = c & 7;
      *(uint4*)(Vl + d * 64 + ((c8 ^ (d & 7)) * 8)) = vu[it];
    }
    __syncthreads();

    // ---- QK^T: 32 q x 64 k per wave ----
    f32x4 s[2][4];
#pragma unroll
    for (int mt = 0; mt < 2; ++mt)
#pragma unroll
      for (int nt = 0; nt < 4; ++nt) s[mt][nt] = (f32x4){0.f, 0.f, 0.f, 0.f};
#pragma unroll
    for (int ds = 0; ds < 4; ++ds) {
#pragma unroll
      for (int nt = 0; nt < 4; ++nt) {
        const int row = nt * 16 + l15;
        bf16x8 kf = *(const bf16x8*)(Kl + row * 128 + (((ds * 4 + quad) ^ (l15 & 7)) * 8));
        s[0][nt] = __builtin_amdgcn_mfma_f32_16x16x32_bf16(qf[0][ds], kf, s[0][nt], 0, 0, 0);
        s[1][nt] = __builtin_amdgcn_mfma_f32_16x16x32_bf16(qf[1][ds], kf, s[1][nt], 0, 0, 0);
      }
    }

    // ---- mask (block-uniform fast path) ----
    if (kb + 64 > kend_blk) {
#pragma unroll
      for (int mt = 0; mt < 2; ++mt)
#pragma unroll
        for (int nt = 0; nt < 4; ++nt) {
          const int col = kb + nt * 16 + l15;
#pragma unroll
          for (int r = 0; r < 4; ++r)
            if (col >= kendv[mt][r]) s[mt][nt][r] = -3.0e38f;
        }
    }

    // ---- register softmax: row max via shfl butterflies ----
    f32x4 alpha[2];
    int need_resc = 0;
#pragma unroll
    for (int mt = 0; mt < 2; ++mt) {
      f32x4 mx;
#pragma unroll
      for (int r = 0; r < 4; ++r)
        mx[r] = fmaxf(fmaxf(s[mt][0][r], s[mt][1][r]), fmaxf(s[mt][2][r], s[mt][3][r]));
#pragma unroll
      for (int r = 0; r < 4; ++r) {
        float v = mx[r];
        v = fmaxf(v, __shfl_xor(v, 1));
        v = fmaxf(v, __shfl_xor(v, 2));
        v = fmaxf(v, __shfl_xor(v, 4));
        v = fmaxf(v, __shfl_xor(v, 8));
        mx[r] = v;
      }
#pragma unroll
      for (int r = 0; r < 4; ++r) {
        const float m_new = fmaxf(m_run[mt][r], mx[r]);
        alpha[mt][r] = __expf(m_run[mt][r] - m_new);
        m_run[mt][r] = m_new;
        need_resc |= (alpha[mt][r] != 1.0f);
      }
    }
    if (__any(need_resc)) {
#pragma unroll
      for (int mt = 0; mt < 2; ++mt)
#pragma unroll
        for (int nt = 0; nt < 9; ++nt)
#pragma unroll
          for (int r = 0; r < 4; ++r) oacc[mt][nt][r] *= alpha[mt][r];
    }

    // ---- P = exp(s - m), store bf16 to per-wave Pl[q][key] ----
#pragma unroll
    for (int mt = 0; mt < 2; ++mt)
#pragma unroll
      for (int nt = 0; nt < 4; ++nt)
#pragma unroll
        for (int r = 0; r < 4; ++r) {
          const float p = __expf(s[mt][nt][r] - m_run[mt][r]);
          Pl[wave][(mt * 16 + quad * 4 + r) * 72 + nt * 16 + l15] = (bf16_t)p;
        }
    __builtin_amdgcn_wave_barrier();

    // ---- PV (+ ones tile accumulates denominator in nt=8) ----
    bf16x8 pf[2][2];
#pragma unroll
    for (int mt = 0; mt < 2; ++mt)
#pragma unroll
      for (int kk = 0; kk < 2; ++kk)
        pf[mt][kk] = *(const bf16x8*)(&Pl[wave][(mt * 16 + l15) * 72 + kk * 32 + quad * 8]);
#pragma unroll
    for (int kk = 0; kk < 2; ++kk) {
#pragma unroll
      for (int nt = 0; nt < 9; ++nt) {
        const int row = nt * 16 + l15;
        bf16x8 vf = *(const bf16x8*)(Vl + row * 64 + (((kk * 4 + quad) ^ (l15 & 7)) * 8));
        oacc[0][nt] = __builtin_amdgcn_mfma_f32_16x16x32_bf16(pf[0][kk], vf, oacc[0][nt], 0, 0, 0);
        oacc[1][nt] = __builtin_amdgcn_mfma_f32_16x16x32_bf16(pf[1][kk], vf, oacc[1][nt], 0, 0, 0);
      }
    }
  }

  // ---- epilogue: normalize by denominator (col 0 of nt=8 tile) and store ----
  float li[2][4];
#pragma unroll
  for (int mt = 0; mt < 2; ++mt)
#pragma unroll
    for (int r = 0; r < 4; ++r) {
      const float lv = __shfl(oacc[mt][8][r], lane & 48);  // lane (quad,0) holds the sum
      li[mt][r] = 1.0f / lv;
    }
#pragma unroll
  for (int mt = 0; mt < 2; ++mt) {
#pragma unroll
    for (int nt = 0; nt < 8; ++nt) {
      const int n = h * HD + nt * 16 + l15;
#pragma unroll
      for (int r = 0; r < 4; ++r) {
        const int row = qw + mt * 16 + quad * 4 + r;
        if (row < L_TOK)
          O[(size_t)row * DIM + n] = (bf16_t)(oacc[mt][nt][r] * li[mt][r]);
      }
    }
  }
}

// ---------------- output projection: out = A * Wo^T + bo (fp32 out) ----------------
__global__ __launch_bounds__(256) void gemm_proj(
    const bf16_t* __restrict__ A, const bf16_t* __restrict__ W,
    const float* __restrict__ bias, float* __restrict__ out)
{
  __shared__ __align__(16) bf16_t Al[128 * 32];
  __shared__ __align__(16) bf16_t Bl[128 * 32];
  const int m0 = blockIdx.x * 128;
  const int n0 = blockIdx.y * 128;

  const int tid = threadIdx.x;
  const int wave = tid >> 6, lane = tid & 63;
  const int quad = lane >> 4, l15 = lane & 15;
  const int wm = (wave >> 1) * 64, wn = (wave & 1) * 64;

  f32x4 acc[4][4];
#pragma unroll
  for (int i = 0; i < 4; ++i)
#pragma unroll
    for (int j = 0; j < 4; ++j) acc[i][j] = (f32x4){0.f, 0.f, 0.f, 0.f};

  const int c0 = wave * 2;
  const int fi0 = c0 * 512 + lane * 8;
  const int r0 = fi0 >> 5, col0 = fi0 & 31;
  const int fi1 = fi0 + 512;
  const int r1 = fi1 >> 5, col1 = fi1 & 31;

  const bf16_t* agp0 = A + (size_t)(m0 + r0) * DIM + col0;
  const bf16_t* agp1 = A + (size_t)(m0 + r1) * DIM + col1;
  const bf16_t* bgp0 = W + (size_t)(n0 + r0) * DIM + col0;
  const bf16_t* bgp1 = W + (size_t)(n0 + r1) * DIM + col1;
  bf16_t* al0 = Al + c0 * 512 + lane * 8;
  bf16_t* al1 = al0 + 512;
  bf16_t* bl0 = Bl + c0 * 512 + lane * 8;
  bf16_t* bl1 = bl0 + 512;

  for (int k0 = 0; k0 < DIM; k0 += 32) {
    __syncthreads();
    gl_lds16(agp0 + k0, al0);
    gl_lds16(agp1 + k0, al1);
    gl_lds16(bgp0 + k0, bl0);
    gl_lds16(bgp1 + k0, bl1);
    __syncthreads();
    bf16x8 af[4], bfg[4];
#pragma unroll
    for (int i = 0; i < 4; ++i) {
      af[i]  = *(const bf16x8*)(Al + (wm + i * 16 + l15) * 32 + quad * 8);
      bfg[i] = *(const bf16x8*)(Bl + (wn + i * 16 + l15) * 32 + quad * 8);
    }
#pragma unroll
    for (int i = 0; i < 4; ++i)
#pragma unroll
      for (int j = 0; j < 4; ++j)
        acc[i][j] = __builtin_amdgcn_mfma_f32_16x16x32_bf16(af[i], bfg[j], acc[i][j], 0, 0, 0);
  }

#pragma unroll
  for (int i = 0; i < 4; ++i) {
#pragma unroll
    for (int j = 0; j < 4; ++j) {
      const int n = n0 + wn + j * 16 + l15;
      const float bb = bias[n];
#pragma unroll
      for (int r = 0; r < 4; ++r) {
        const int m = m0 + wm + i * 16 + quad * 4 + r;
        if (m < L_TOK) out[(size_t)m * DIM + n] = acc[i][j][r] + bb;
      }
    }
  }
}

extern "C" void kernel_launch(void* const* d_in, const int* in_sizes, int n_in,
                              void* d_out, int out_size, void* d_ws, size_t ws_size,
                              hipStream_t stream) {
  (void)in_sizes; (void)n_in; (void)out_size;
  const float* x  = (const float*)d_in[0];
  const float* fr = (const float*)d_in[1];
  const float* Wq = (const float*)d_in[2];
  const float* bq = (const float*)d_in[3];
  const float* Wk = (const float*)d_in[4];
  const float* bk = (const float*)d_in[5];
  const float* Wv = (const float*)d_in[6];
  const float* bv = (const float*)d_in[7];
  const float* Wo = (const float*)d_in[8];
  const float* bo = (const float*)d_in[9];
  const float* gq = (const float*)d_in[10];
  const float* gk = (const float*)d_in[11];
  float* out = (float*)d_out;

  char* ws = (char*)d_ws;
  size_t off = 0;
  auto alloc = [&](size_t bytes) {
    char* p = ws + off;
    off += (bytes + 255) & ~(size_t)255;
    return p;
  };
  const size_t lbuf = (size_t)LPAD * DIM * 2;
  const size_t wbuf = (size_t)DIM * DIM * 2;
  bf16_t* xb  = (bf16_t*)alloc(lbuf);
  bf16_t* Wqb = (bf16_t*)alloc(wbuf);
  bf16_t* Wkb = (bf16_t*)alloc(wbuf);
  bf16_t* Wvb = (bf16_t*)alloc(wbuf);
  bf16_t* Wob = (bf16_t*)alloc(wbuf);
  bf16_t* Qb  = (bf16_t*)alloc(lbuf);
  bf16_t* Kb  = (bf16_t*)alloc(lbuf);
  bf16_t* Vtb = (bf16_t*)alloc(lbuf);
  bf16_t* Ob  = (bf16_t*)alloc(lbuf);
  if (off > ws_size) return;

  const int n4x = L_TOK * DIM / 4;
  const int n4w = DIM * DIM / 4;
  cast_f32_bf16<<<(n4x + 255) / 256, 256, 0, stream>>>(x, xb, n4x);
  cast_f32_bf16<<<(n4w + 255) / 256, 256, 0, stream>>>(Wq, Wqb, n4w);
  cast_f32_bf16<<<(n4w + 255) / 256, 256, 0, stream>>>(Wk, Wkb, n4w);
  cast_f32_bf16<<<(n4w + 255) / 256, 256, 0, stream>>>(Wv, Wvb, n4w);
  cast_f32_bf16<<<(n4w + 255) / 256, 256, 0, stream>>>(Wo, Wob, n4w);

  gemm_qkv<<<dim3(LPAD / 128, 36), 256, 0, stream>>>(xb, Wqb, Wkb, Wvb, bq, bk, bv,
                                                     Qb, Kb, Vtb);
  rmsnorm_rope<<<L_TOK, 256, 0, stream>>>(Qb, Kb, gq, gk, fr);
  attn<<<dim3(LPAD / 128, NH), 256, 0, stream>>>(Qb, Kb, Vtb, Ob);
  gemm_proj<<<dim3(LPAD / 128, 12), 256, 0, stream>>>(Ob, Wob, bo, out);
}

// Round 5
// 576.629 us; speedup vs baseline: 1.6319x; 1.6319x over previous
//
#include <hip/hip_runtime.h>
#include <hip/hip_bf16.h>
#include <math.h>

typedef __bf16 bf16_t;
typedef __attribute__((ext_vector_type(8))) __bf16 bf16x8;
typedef __attribute__((ext_vector_type(4))) __bf16 bf16x4;
typedef __attribute__((ext_vector_type(4))) float f32x4;
typedef __attribute__((ext_vector_type(4))) short s16x4;

#define L_TOK 4680
#define DIM   1536
#define NH    12
#define HD    128
#define FRAME 1560
#define LPAD  4736
#define SCALE 0.08838834764831845f   // 1/sqrt(128)

union PU { bf16x4 h; s16x4 s; };

// v_mfma_f32_16x16x16_bf16 (gfx950 ISA §10: A/B = 2 VGPRs = 4 bf16).
// Host pass has no amdgcn builtins -> stub (never executed on host).
static __device__ __forceinline__ f32x4 mfma16(const PU& a, const PU& b, f32x4 c) {
#if defined(__HIP_DEVICE_COMPILE__)
  return __builtin_amdgcn_mfma_f32_16x16x16bf16_1k(a.s, b.s, c, 0, 0, 0);
#else
  (void)a; (void)b;
  return c;
#endif
}

__device__ __forceinline__ void gl_lds16(const bf16_t* g, bf16_t* l) {
  __builtin_amdgcn_global_load_lds(
      (const __attribute__((address_space(1))) unsigned int*)(g),
      (__attribute__((address_space(3))) unsigned int*)(l),
      16, 0, 0);
}

// ---------------- fp32 -> bf16 cast ----------------
__global__ __launch_bounds__(256) void cast_f32_bf16(const float* __restrict__ in,
                                                     bf16_t* __restrict__ out, int n4) {
  int i = blockIdx.x * 256 + threadIdx.x;
  if (i >= n4) return;
  float4 v = ((const float4*)in)[i];
  bf16x4 o;
  o[0] = (__bf16)v.x; o[1] = (__bf16)v.y; o[2] = (__bf16)v.z; o[3] = (__bf16)v.w;
  ((bf16x4*)out)[i] = o;
}

// ---------------- fused QKV GEMM: C = X * W^T + b ----------------
__global__ __launch_bounds__(256) void gemm_qkv(
    const bf16_t* __restrict__ X,
    const bf16_t* __restrict__ Wq, const bf16_t* __restrict__ Wk, const bf16_t* __restrict__ Wv,
    const float* __restrict__ bq, const float* __restrict__ bk, const float* __restrict__ bv,
    bf16_t* __restrict__ Qo, bf16_t* __restrict__ Ko, bf16_t* __restrict__ Vt)
{
  __shared__ __align__(16) bf16_t Al[128 * 32];
  __shared__ __align__(16) bf16_t Bl[128 * 32];
  const int m0 = blockIdx.x * 128;
  const int nb = blockIdx.y;
  const int seg = nb / 12;
  const int n0 = (nb % 12) * 128;
  const bf16_t* W   = (seg == 0) ? Wq : (seg == 1) ? Wk : Wv;
  const float* bias = (seg == 0) ? bq : (seg == 1) ? bk : bv;

  const int tid = threadIdx.x;
  const int wave = tid >> 6, lane = tid & 63;
  const int quad = lane >> 4, l15 = lane & 15;
  const int wm = (wave >> 1) * 64, wn = (wave & 1) * 64;

  f32x4 acc[4][4];
#pragma unroll
  for (int i = 0; i < 4; ++i)
#pragma unroll
    for (int j = 0; j < 4; ++j) acc[i][j] = (f32x4){0.f, 0.f, 0.f, 0.f};

  const int c0 = wave * 2;
  const int fi0 = c0 * 512 + lane * 8;
  const int r0 = fi0 >> 5, col0 = fi0 & 31;
  const int fi1 = fi0 + 512;
  const int r1 = fi1 >> 5, col1 = fi1 & 31;

  const bf16_t* agp0 = X + (size_t)(m0 + r0) * DIM + col0;
  const bf16_t* agp1 = X + (size_t)(m0 + r1) * DIM + col1;
  const bf16_t* bgp0 = W + (size_t)(n0 + r0) * DIM + col0;
  const bf16_t* bgp1 = W + (size_t)(n0 + r1) * DIM + col1;
  bf16_t* al0 = Al + c0 * 512 + lane * 8;
  bf16_t* al1 = al0 + 512;
  bf16_t* bl0 = Bl + c0 * 512 + lane * 8;
  bf16_t* bl1 = bl0 + 512;

  for (int k0 = 0; k0 < DIM; k0 += 32) {
    __syncthreads();
    gl_lds16(agp0 + k0, al0);
    gl_lds16(agp1 + k0, al1);
    gl_lds16(bgp0 + k0, bl0);
    gl_lds16(bgp1 + k0, bl1);
    __syncthreads();
    bf16x8 af[4], bfg[4];
#pragma unroll
    for (int i = 0; i < 4; ++i) {
      af[i]  = *(const bf16x8*)(Al + (wm + i * 16 + l15) * 32 + quad * 8);
      bfg[i] = *(const bf16x8*)(Bl + (wn + i * 16 + l15) * 32 + quad * 8);
    }
#pragma unroll
    for (int i = 0; i < 4; ++i)
#pragma unroll
      for (int j = 0; j < 4; ++j)
        acc[i][j] = __builtin_amdgcn_mfma_f32_16x16x32_bf16(af[i], bfg[j], acc[i][j], 0, 0, 0);
  }

  if (seg < 2) {
    bf16_t* Out = (seg == 0) ? Qo : Ko;
#pragma unroll
    for (int i = 0; i < 4; ++i) {
#pragma unroll
      for (int j = 0; j < 4; ++j) {
        const int n = n0 + wn + j * 16 + l15;
        const float bb = bias[n];
#pragma unroll
        for (int r = 0; r < 4; ++r) {
          const int m = m0 + wm + i * 16 + quad * 4 + r;
          if (m < L_TOK) Out[(size_t)m * DIM + n] = (bf16_t)(acc[i][j][r] + bb);
        }
      }
    }
  } else {
#pragma unroll
    for (int i = 0; i < 4; ++i) {
      const int mb = m0 + wm + i * 16 + quad * 4;
      if (mb < L_TOK) {
#pragma unroll
        for (int j = 0; j < 4; ++j) {
          const int n = n0 + wn + j * 16 + l15;
          const float bb = bias[n];
          bf16x4 p;
          p[0] = (__bf16)(acc[i][j][0] + bb);
          p[1] = (__bf16)(acc[i][j][1] + bb);
          p[2] = (__bf16)(acc[i][j][2] + bb);
          p[3] = (__bf16)(acc[i][j][3] + bb);
          *(bf16x4*)(Vt + (size_t)n * LPAD + mb) = p;
        }
      }
    }
  }
}

// ---------------- RMSNorm + RoPE, in place on Q and K ----------------
__global__ __launch_bounds__(256) void rmsnorm_rope(
    bf16_t* __restrict__ Q, bf16_t* __restrict__ K,
    const float* __restrict__ gq, const float* __restrict__ gk,
    const float* __restrict__ freqs)
{
  const int l = blockIdx.x;
  const int tid = threadIdx.x;
  const int wave = tid >> 6, lane = tid & 63;
  bf16_t* qrow = Q + (size_t)l * DIM;
  bf16_t* krow = K + (size_t)l * DIM;

  unsigned int qb[3], kb[3];
  float sq = 0.f, sk = 0.f;
#pragma unroll
  for (int s = 0; s < 3; ++s) {
    const int p = s * 256 + tid;
    qb[s] = *(const unsigned int*)(qrow + 2 * p);
    kb[s] = *(const unsigned int*)(krow + 2 * p);
    const __bf16* qh = (const __bf16*)&qb[s];
    const __bf16* kh = (const __bf16*)&kb[s];
    const float q0 = (float)qh[0], q1 = (float)qh[1];
    const float k0 = (float)kh[0], k1 = (float)kh[1];
    sq += q0 * q0 + q1 * q1;
    sk += k0 * k0 + k1 * k1;
  }
#pragma unroll
  for (int off = 1; off < 64; off <<= 1) {
    sq += __shfl_xor(sq, off);
    sk += __shfl_xor(sk, off);
  }
  __shared__ float rq_s[4], rk_s[4];
  if (lane == 0) { rq_s[wave] = sq; rk_s[wave] = sk; }
  __syncthreads();
  sq = rq_s[0] + rq_s[1] + rq_s[2] + rq_s[3];
  sk = rk_s[0] + rk_s[1] + rk_s[2] + rk_s[3];
  const float rnq = rsqrtf(sq * (1.f / DIM) + 1e-6f);
  const float rnk = rsqrtf(sk * (1.f / DIM) + 1e-6f);

  const int t = l / FRAME;
  const int rem = l - t * FRAME;
  const int hh = rem / 52;
  const int ww = rem - hh * 52;

#pragma unroll
  for (int s = 0; s < 3; ++s) {
    const int p = s * 256 + tid;
    const int j = p & 63;
    const int sel = (j < 22) ? t : (j < 43) ? hh : ww;
    const float ang = freqs[sel * 64 + j];
    float sn, cs;
    __sincosf(ang, &sn, &cs);
    const __bf16* qh = (const __bf16*)&qb[s];
    const __bf16* kh = (const __bf16*)&kb[s];
    {
      const float g0 = gq[2 * p], g1 = gq[2 * p + 1];
      const float re = (float)qh[0] * rnq * g0;
      const float im = (float)qh[1] * rnq * g1;
      unsigned int o;
      __bf16* oh = (__bf16*)&o;
      oh[0] = (__bf16)((re * cs - im * sn) * SCALE);
      oh[1] = (__bf16)((re * sn + im * cs) * SCALE);
      *(unsigned int*)(qrow + 2 * p) = o;
    }
    {
      const float g0 = gk[2 * p], g1 = gk[2 * p + 1];
      const float re = (float)kh[0] * rnk * g0;
      const float im = (float)kh[1] * rnk * g1;
      unsigned int o;
      __bf16* oh = (__bf16*)&o;
      oh[0] = (__bf16)(re * cs - im * sn);
      oh[1] = (__bf16)(re * sn + im * cs);
      *(unsigned int*)(krow + 2 * p) = o;
    }
  }
}

// ---------------- flash attention v3 ----------------
// block = 128q x head (x slice); 4 waves x 32 q-rows; 64-key tiles.
// S^T = MFMA16x16x32(A=K, B=Q): lane holds q=l15 (uniform), keys quad*4+r.
// PV  = MFMA16x16x16(A=V^T, B=P): P-frag == S^T C-layout registers (zero movement).
// oacc is D'[d][q]: q=l15 aligned with alpha -> no transposes anywhere.
template <bool SPLIT2>
__global__ __launch_bounds__(256) void attn(
    const bf16_t* __restrict__ Q, const bf16_t* __restrict__ K,
    const bf16_t* __restrict__ Vt, bf16_t* __restrict__ O,
    float* __restrict__ Opart, float* __restrict__ Mp, float* __restrict__ Lp)
{
  __shared__ __align__(16) bf16_t Kl[64 * 128];  // [key][d], 16B chunks ^ (key&7)
  __shared__ __align__(16) bf16_t Vl[128 * 64];  // [d][key], 16B chunks ^ (d&7)

  const int qb = (int)gridDim.x - 1 - (int)blockIdx.x;  // heavy tiles first
  const int h  = blockIdx.y;
  const int slice = SPLIT2 ? blockIdx.z : 0;
  const int NS = SPLIT2 ? 2 : 1;
  const int tid = threadIdx.x;
  const int wave = tid >> 6, lane = tid & 63;
  const int quad = lane >> 4, l15 = lane & 15;
  const int e7 = l15 & 7, qh2 = quad >> 1, ql1 = quad & 1;
  const int q0 = qb * 128;
  const int qw = q0 + wave * 32;

  // Q fragments (B-operand layout == A layout): qf[qt][ds]
  bf16x8 qf[2][4];
#pragma unroll
  for (int qt = 0; qt < 2; ++qt) {
    const int qrow = qw + qt * 16 + l15;
    const bf16_t* qp = Q + (size_t)qrow * DIM + h * HD + quad * 8;
#pragma unroll
    for (int ds = 0; ds < 4; ++ds) qf[qt][ds] = *(const bf16x8*)(qp + ds * 32);
  }

  int kendq[2];
#pragma unroll
  for (int qt = 0; qt < 2; ++qt) {
    int row = qw + qt * 16 + l15;
    if (row > L_TOK - 1) row = L_TOK - 1;
    kendq[qt] = FRAME * (row / FRAME + 1);
  }
  const int kend_blk = FRAME * (q0 / FRAME + 1);

  float m_run[2] = {-3.0e38f, -3.0e38f};
  float l_run[2] = {0.f, 0.f};
  f32x4 oacc[2][8];
#pragma unroll
  for (int qt = 0; qt < 2; ++qt)
#pragma unroll
    for (int nt = 0; nt < 8; ++nt) oacc[qt][nt] = (f32x4){0.f, 0.f, 0.f, 0.f};

  int lastl = q0 + 127; if (lastl > L_TOK - 1) lastl = L_TOK - 1;
  const int nkt = (FRAME * (lastl / FRAME + 1) + 63) >> 6;

  for (int kt = slice; kt < nkt; kt += NS) {
    const int kb = kt * 64;
    __syncthreads();
    // stage K and V tiles (loads first, then swizzled stores)
    uint4 tk[2], tv[2];
#pragma unroll
    for (int it = 0; it < 2; ++it) {
      const int c = tid + it * 512;
      const int r = c >> 4, cc = c & 15;
      tk[it] = *(const uint4*)(K + (size_t)(kb + r) * DIM + h * HD + cc * 8);
      const int d = c >> 3, c8 = c & 7;
      tv[it] = *(const uint4*)(Vt + (size_t)(h * HD + d) * LPAD + kb + c8 * 8);
    }
    uint4 tk2[2], tv2[2];
#pragma unroll
    for (int it = 0; it < 2; ++it) {
      const int c = tid + 256 + it * 512;
      const int r = c >> 4, cc = c & 15;
      tk2[it] = *(const uint4*)(K + (size_t)(kb + r) * DIM + h * HD + cc * 8);
      const int d = c >> 3, c8 = c & 7;
      tv2[it] = *(const uint4*)(Vt + (size_t)(h * HD + d) * LPAD + kb + c8 * 8);
    }
#pragma unroll
    for (int it = 0; it < 2; ++it) {
      const int c = tid + it * 512;
      const int r = c >> 4, cc = c & 15;
      *(uint4*)(Kl + r * 128 + ((cc ^ (r & 7)) * 8)) = tk[it];
      const int d = c >> 3, c8 = c & 7;
      *(uint4*)(Vl + d * 64 + ((c8 ^ (d & 7)) * 8)) = tv[it];
    }
#pragma unroll
    for (int it = 0; it < 2; ++it) {
      const int c = tid + 256 + it * 512;
      const int r = c >> 4, cc = c & 15;
      *(uint4*)(Kl + r * 128 + ((cc ^ (r & 7)) * 8)) = tk2[it];
      const int d = c >> 3, c8 = c & 7;
      *(uint4*)(Vl + d * 64 + ((c8 ^ (d & 7)) * 8)) = tv2[it];
    }
    __syncthreads();

    // ---- S^T: D[key][q]; lane: key = kb + t4*16 + quad*4 + r, q = qw + qt*16 + l15
    f32x4 s[4][2];
#pragma unroll
    for (int t4 = 0; t4 < 4; ++t4)
#pragma unroll
      for (int qt = 0; qt < 2; ++qt) s[t4][qt] = (f32x4){0.f, 0.f, 0.f, 0.f};
#pragma unroll
    for (int ds = 0; ds < 4; ++ds) {
      bf16x8 kf[4];
#pragma unroll
      for (int t4 = 0; t4 < 4; ++t4)
        kf[t4] = *(const bf16x8*)(Kl + (t4 * 16 + l15) * 128 + (((ds * 4 + quad) ^ e7) * 8));
#pragma unroll
      for (int t4 = 0; t4 < 4; ++t4) {
        s[t4][0] = __builtin_amdgcn_mfma_f32_16x16x32_bf16(kf[t4], qf[0][ds], s[t4][0], 0, 0, 0);
        s[t4][1] = __builtin_amdgcn_mfma_f32_16x16x32_bf16(kf[t4], qf[1][ds], s[t4][1], 0, 0, 0);
      }
    }

    // ---- mask (block-uniform fast path); key/kend per-lane in registers
    if (kb + 64 > kend_blk) {
#pragma unroll
      for (int t4 = 0; t4 < 4; ++t4)
#pragma unroll
        for (int qt = 0; qt < 2; ++qt)
#pragma unroll
          for (int r = 0; r < 4; ++r) {
            const int key = kb + t4 * 16 + quad * 4 + r;
            if (key >= kendq[qt]) s[t4][qt][r] = -3.0e38f;
          }
    }

    // ---- softmax (all-register; 2 shfl per qt for max, 2 for sum)
    float alpha[2];
    int need = 0;
#pragma unroll
    for (int qt = 0; qt < 2; ++qt) {
      f32x4 m4;
#pragma unroll
      for (int r = 0; r < 4; ++r)
        m4[r] = fmaxf(fmaxf(s[0][qt][r], s[1][qt][r]), fmaxf(s[2][qt][r], s[3][qt][r]));
      float mx = fmaxf(fmaxf(m4[0], m4[1]), fmaxf(m4[2], m4[3]));
      mx = fmaxf(mx, __shfl_xor(mx, 16));
      mx = fmaxf(mx, __shfl_xor(mx, 32));
      const float m_new = fmaxf(m_run[qt], mx);
      alpha[qt] = __expf(m_run[qt] - m_new);
      m_run[qt] = m_new;
      need |= (alpha[qt] != 1.0f);
    }
    if (__any(need)) {
#pragma unroll
      for (int qt = 0; qt < 2; ++qt)
#pragma unroll
        for (int nt = 0; nt < 8; ++nt)
#pragma unroll
          for (int r = 0; r < 4; ++r) oacc[qt][nt][r] *= alpha[qt];
    }

    // ---- P = exp(s-m): pack bf16 (stays in registers as PV B-frags)
    PU u[4][2];
#pragma unroll
    for (int qt = 0; qt < 2; ++qt) {
      f32x4 a4 = (f32x4){0.f, 0.f, 0.f, 0.f};
#pragma unroll
      for (int t4 = 0; t4 < 4; ++t4) {
#pragma unroll
        for (int r = 0; r < 4; ++r) {
          const float e = __expf(s[t4][qt][r] - m_run[qt]);
          u[t4][qt].h[r] = (bf16_t)e;
          a4[r] += e;
        }
      }
      float ssum = (a4[0] + a4[1]) + (a4[2] + a4[3]);
      ssum += __shfl_xor(ssum, 16);
      ssum += __shfl_xor(ssum, 32);
      l_run[qt] = l_run[qt] * alpha[qt] + ssum;
    }

    // ---- PV: D'[d][q] += V^T P^T ; A-frag b64 from Vl, B-frag = u (registers)
#pragma unroll
    for (int t4 = 0; t4 < 4; ++t4) {
#pragma unroll
      for (int nt = 0; nt < 8; ++nt) {
        const int row = nt * 16 + l15;
        PU vf;
        vf.h = *(const bf16x4*)(Vl + row * 64 + (((t4 * 2 + qh2) ^ e7) * 8) + ql1 * 4);
        oacc[0][nt] = mfma16(vf, u[t4][0], oacc[0][nt]);
        oacc[1][nt] = mfma16(vf, u[t4][1], oacc[1][nt]);
      }
    }
  }

  // ---- epilogue: lane holds d = nt*16+quad*4+r, q = qw+qt*16+l15
  if (!SPLIT2) {
#pragma unroll
    for (int qt = 0; qt < 2; ++qt) {
      const float inv = 1.0f / l_run[qt];
      const int q = qw + qt * 16 + l15;
#pragma unroll
      for (int nt = 0; nt < 8; ++nt) {
        bf16x4 o;
#pragma unroll
        for (int r = 0; r < 4; ++r) o[r] = (bf16_t)(oacc[qt][nt][r] * inv);
        *(bf16x4*)(O + (size_t)q * DIM + h * HD + nt * 16 + quad * 4) = o;
      }
    }
  } else {
#pragma unroll
    for (int qt = 0; qt < 2; ++qt) {
      const int q = qw + qt * 16 + l15;
      float* op = Opart + ((size_t)slice * LPAD + q) * DIM + h * HD;
#pragma unroll
      for (int nt = 0; nt < 8; ++nt)
        *(f32x4*)(op + nt * 16 + quad * 4) = oacc[qt][nt];
      if (quad == 0) {
        Mp[(slice * NH + h) * LPAD + q] = m_run[qt];
        Lp[(slice * NH + h) * LPAD + q] = l_run[qt];
      }
    }
  }
}

// ---------------- merge the two K-slices ----------------
__global__ __launch_bounds__(256) void attn_merge(
    const float* __restrict__ Op, const float* __restrict__ Mp,
    const float* __restrict__ Lp, bf16_t* __restrict__ Ob)
{
  const int idx = blockIdx.x * 256 + threadIdx.x;   // f32x4 index over LPAD*DIM/4
  const int q = idx / (DIM / 4);
  const int c4 = idx - q * (DIM / 4);
  const int h = c4 >> 5;                            // HD/4 = 32 vec4 per head
  const float m0 = Mp[h * LPAD + q];
  const float m1 = Mp[(NH + h) * LPAD + q];
  const float l0 = Lp[h * LPAD + q];
  const float l1 = Lp[(NH + h) * LPAD + q];
  const float M = fmaxf(m0, m1);
  float w0 = __expf(m0 - M), w1 = __expf(m1 - M);
  const float inv = 1.0f / (l0 * w0 + l1 * w1);
  w0 *= inv; w1 *= inv;
  const float4 o0 = ((const float4*)Op)[idx];
  const float4 o1 = ((const float4*)Op)[idx + (size_t)LPAD * DIM / 4];
  bf16x4 o;
  o[0] = (bf16_t)(o0.x * w0 + o1.x * w1);
  o[1] = (bf16_t)(o0.y * w0 + o1.y * w1);
  o[2] = (bf16_t)(o0.z * w0 + o1.z * w1);
  o[3] = (bf16_t)(o0.w * w0 + o1.w * w1);
  ((bf16x4*)Ob)[idx] = o;
}

// ---------------- output projection: out = A * Wo^T + bo (fp32 out) ----------------
__global__ __launch_bounds__(256) void gemm_proj(
    const bf16_t* __restrict__ A, const bf16_t* __restrict__ W,
    const float* __restrict__ bias, float* __restrict__ out)
{
  __shared__ __align__(16) bf16_t Al[128 * 32];
  __shared__ __align__(16) bf16_t Bl[128 * 32];
  const int m0 = blockIdx.x * 128;
  const int n0 = blockIdx.y * 128;

  const int tid = threadIdx.x;
  const int wave = tid >> 6, lane = tid & 63;
  const int quad = lane >> 4, l15 = lane & 15;
  const int wm = (wave >> 1) * 64, wn = (wave & 1) * 64;

  f32x4 acc[4][4];
#pragma unroll
  for (int i = 0; i < 4; ++i)
#pragma unroll
    for (int j = 0; j < 4; ++j) acc[i][j] = (f32x4){0.f, 0.f, 0.f, 0.f};

  const int c0 = wave * 2;
  const int fi0 = c0 * 512 + lane * 8;
  const int r0 = fi0 >> 5, col0 = fi0 & 31;
  const int fi1 = fi0 + 512;
  const int r1 = fi1 >> 5, col1 = fi1 & 31;

  const bf16_t* agp0 = A + (size_t)(m0 + r0) * DIM + col0;
  const bf16_t* agp1 = A + (size_t)(m0 + r1) * DIM + col1;
  const bf16_t* bgp0 = W + (size_t)(n0 + r0) * DIM + col0;
  const bf16_t* bgp1 = W + (size_t)(n0 + r1) * DIM + col1;
  bf16_t* al0 = Al + c0 * 512 + lane * 8;
  bf16_t* al1 = al0 + 512;
  bf16_t* bl0 = Bl + c0 * 512 + lane * 8;
  bf16_t* bl1 = bl0 + 512;

  for (int k0 = 0; k0 < DIM; k0 += 32) {
    __syncthreads();
    gl_lds16(agp0 + k0, al0);
    gl_lds16(agp1 + k0, al1);
    gl_lds16(bgp0 + k0, bl0);
    gl_lds16(bgp1 + k0, bl1);
    __syncthreads();
    bf16x8 af[4], bfg[4];
#pragma unroll
    for (int i = 0; i < 4; ++i) {
      af[i]  = *(const bf16x8*)(Al + (wm + i * 16 + l15) * 32 + quad * 8);
      bfg[i] = *(const bf16x8*)(Bl + (wn + i * 16 + l15) * 32 + quad * 8);
    }
#pragma unroll
    for (int i = 0; i < 4; ++i)
#pragma unroll
      for (int j = 0; j < 4; ++j)
        acc[i][j] = __builtin_amdgcn_mfma_f32_16x16x32_bf16(af[i], bfg[j], acc[i][j], 0, 0, 0);
  }

#pragma unroll
  for (int i = 0; i < 4; ++i) {
#pragma unroll
    for (int j = 0; j < 4; ++j) {
      const int n = n0 + wn + j * 16 + l15;
      const float bb = bias[n];
#pragma unroll
      for (int r = 0; r < 4; ++r) {
        const int m = m0 + wm + i * 16 + quad * 4 + r;
        if (m < L_TOK) out[(size_t)m * DIM + n] = acc[i][j][r] + bb;
      }
    }
  }
}

extern "C" void kernel_launch(void* const* d_in, const int* in_sizes, int n_in,
                              void* d_out, int out_size, void* d_ws, size_t ws_size,
                              hipStream_t stream) {
  (void)in_sizes; (void)n_in; (void)out_size;
  const float* x  = (const float*)d_in[0];
  const float* fr = (const float*)d_in[1];
  const float* Wq = (const float*)d_in[2];
  const float* bq = (const float*)d_in[3];
  const float* Wk = (const float*)d_in[4];
  const float* bk = (const float*)d_in[5];
  const float* Wv = (const float*)d_in[6];
  const float* bv = (const float*)d_in[7];
  const float* Wo = (const float*)d_in[8];
  const float* bo = (const float*)d_in[9];
  const float* gq = (const float*)d_in[10];
  const float* gk = (const float*)d_in[11];
  float* out = (float*)d_out;

  char* ws = (char*)d_ws;
  size_t off = 0;
  auto alloc = [&](size_t bytes) {
    char* p = ws + off;
    off += (bytes + 255) & ~(size_t)255;
    return p;
  };
  const size_t lbuf = (size_t)LPAD * DIM * 2;
  const size_t wbuf = (size_t)DIM * DIM * 2;
  bf16_t* xb  = (bf16_t*)alloc(lbuf);
  bf16_t* Wqb = (bf16_t*)alloc(wbuf);
  bf16_t* Wkb = (bf16_t*)alloc(wbuf);
  bf16_t* Wvb = (bf16_t*)alloc(wbuf);
  bf16_t* Wob = (bf16_t*)alloc(wbuf);
  bf16_t* Qb  = (bf16_t*)alloc(lbuf);
  bf16_t* Kb  = (bf16_t*)alloc(lbuf);
  bf16_t* Vtb = (bf16_t*)alloc(lbuf);
  bf16_t* Ob  = (bf16_t*)alloc(lbuf);
  const size_t base_off = off;
  float* Opart = (float*)alloc((size_t)2 * LPAD * DIM * 4);
  float* Mp    = (float*)alloc((size_t)2 * NH * LPAD * 4);
  float* Lp    = (float*)alloc((size_t)2 * NH * LPAD * 4);
  const bool use_split = (off <= ws_size);
  if (base_off > ws_size) return;

  const int n4x = L_TOK * DIM / 4;
  const int n4w = DIM * DIM / 4;
  cast_f32_bf16<<<(n4x + 255) / 256, 256, 0, stream>>>(x, xb, n4x);
  cast_f32_bf16<<<(n4w + 255) / 256, 256, 0, stream>>>(Wq, Wqb, n4w);
  cast_f32_bf16<<<(n4w + 255) / 256, 256, 0, stream>>>(Wk, Wkb, n4w);
  cast_f32_bf16<<<(n4w + 255) / 256, 256, 0, stream>>>(Wv, Wvb, n4w);
  cast_f32_bf16<<<(n4w + 255) / 256, 256, 0, stream>>>(Wo, Wob, n4w);

  gemm_qkv<<<dim3(LPAD / 128, 36), 256, 0, stream>>>(xb, Wqb, Wkb, Wvb, bq, bk, bv,
                                                     Qb, Kb, Vtb);
  rmsnorm_rope<<<L_TOK, 256, 0, stream>>>(Qb, Kb, gq, gk, fr);
  if (use_split) {
    attn<true><<<dim3(LPAD / 128, NH, 2), 256, 0, stream>>>(Qb, Kb, Vtb, Ob, Opart, Mp, Lp);
    attn_merge<<<(LPAD * DIM / 4) / 256, 256, 0, stream>>>(Opart, Mp, Lp, Ob);
  } else {
    attn<false><<<dim3(LPAD / 128, NH, 1), 256, 0, stream>>>(Qb, Kb, Vtb, Ob, Opart, Mp, Lp);
  }
  gemm_proj<<<dim3(LPAD / 128, 12), 256, 0, stream>>>(Ob, Wob, bo, out);
}